// Round 11
// baseline (2237.363 us; speedup 1.0000x reference)
//
#include <hip/hip_runtime.h>
#include <stdio.h>

#define NBP   8192
#define MTOT  8192
#define CIN   64
#define C1    67
#define C1P   68
#define CO    128

#define EPR(...) do { fprintf(stderr, __VA_ARGS__); fflush(stderr); } while (0)

// ---------------------------------------------------------------------------
// Zero the 1024-float BN-stats region; write output 0 = new_xyz (f32 copy).
// ---------------------------------------------------------------------------
__global__ void StackSAModuleMSG_85761906966880_kernel(
    const float* nxyz, float* out, float* stats)
{
    int i = blockIdx.x * 256 + threadIdx.x;
    if (i < 1024) stats[i] = 0.f;
    if (i < MTOT*3) out[i] = nxyz[i];
}

// ---------------------------------------------------------------------------
// Ball query, both scales, one thread per query; sequential ascending scan.
// d2 computed in DOUBLE so membership matches an f64 numpy gold exactly
// (f32 arithmetic sits ~1e-7 from the boundary and flipped ~1 pair).
// ---------------------------------------------------------------------------
__global__ void sa_ballq(
    const float* xyz, const float* new_xyz,
    int* idx0, int* idx1, int* empty0, int* empty1)
{
    const double r2a = 0.2 * 0.2;   // exact Python double
    const double r2b = 0.4 * 0.4;
    int m = blockIdx.x * 256 + threadIdx.x;
    if (m >= MTOT) return;
    int b    = m >> 11;
    int base = b * NBP;

    double nx = (double)new_xyz[3*m+0];
    double ny = (double)new_xyz[3*m+1];
    double nz = (double)new_xyz[3*m+2];
    double nn = nx*nx + ny*ny + nz*nz;

    int cnt0 = 0, cnt1 = 0;
    int first0 = base, first1 = base;

    for (int j = 0; j < NBP; j++) {
        int gi = base + j;
        double px = (double)xyz[3*gi+0];
        double py = (double)xyz[3*gi+1];
        double pz = (double)xyz[3*gi+2];
        double pp = px*px + py*py + pz*pz;
        double dt = nx*px + ny*py + nz*pz;
        double d2 = nn + pp - 2.0*dt;
        if (d2 < r2a && cnt0 < 16) {
            if (cnt0 == 0) first0 = gi;
            idx0[m*16 + cnt0] = gi;
            cnt0++;
        }
        if (d2 < r2b && cnt1 < 32) {
            if (cnt1 == 0) first1 = gi;
            idx1[m*32 + cnt1] = gi;
            cnt1++;
        }
        if (cnt0 >= 16 && cnt1 >= 32) break;
    }
    for (int k = cnt0; k < 16; k++) idx0[m*16 + k] = first0;
    for (int k = cnt1; k < 32; k++) idx1[m*32 + k] = first1;
    empty0[m] = (cnt0 == 0);
    empty1[m] = (cnt1 == 0);
}

// ---------------------------------------------------------------------------
// Pass 1: gather g=[xyz[idx]-new | feat[idx]] into LDS, x1 = g @ W0^T -> ws,
// accumulate layer-1 per-channel sum/sumsq. Block m, thread t = out channel.
// ---------------------------------------------------------------------------
__global__ void sa_pass1(
    const float* xyz, const float* feat, const float* nxyz,
    const int* idx, const int* empty, const float* w0,
    float* x1, float* ssum, float* ssq, int NS)
{
    __shared__ float gs[32*C1P];
    __shared__ int   lidx[32];
    int m = blockIdx.x, t = threadIdx.x;
    if (t < NS) lidx[t] = idx[m*NS + t];
    __syncthreads();
    int emp = empty[m];
    for (int e = t; e < NS*C1P; e += 128) {
        int n = e / C1P, c = e - n*C1P;
        float v = 0.f;
        if (c < C1 && !emp) {
            int gi = lidx[n];
            v = (c < 3) ? (xyz[3*gi + c] - nxyz[3*m + c])
                        : feat[(long long)gi*CIN + (c-3)];
        }
        gs[e] = v;
    }
    __syncthreads();

    const float* wr = w0 + t*C1;
    float4 w[17];
#pragma unroll
    for (int c = 0; c < 16; c++)
        w[c] = make_float4(wr[4*c], wr[4*c+1], wr[4*c+2], wr[4*c+3]);
    w[16] = make_float4(wr[64], wr[65], wr[66], 0.f);

    float s = 0.f, q = 0.f;
    long long obase = (long long)m*NS*CO + t;
    for (int n = 0; n < NS; n++) {
        const float4* g4 = (const float4*)(gs + n*C1P);
        float acc = 0.f;
#pragma unroll
        for (int c = 0; c < 17; c++) {
            float4 g = g4[c];
            acc = fmaf(g.x, w[c].x, acc);
            acc = fmaf(g.y, w[c].y, acc);
            acc = fmaf(g.z, w[c].z, acc);
            acc = fmaf(g.w, w[c].w, acc);
        }
        x1[obase + (long long)n*CO] = acc;
        s += acc; q = fmaf(acc, acc, q);
    }
    atomicAdd(&ssum[t], s);
    atomicAdd(&ssq[t], q);
}

// ---------------------------------------------------------------------------
// Pass 2: read x1, BN1+ReLU -> LDS, x2 = h @ W1^T written in place,
// accumulate layer-2 stats. Block-private rows: in-place is safe.
// ---------------------------------------------------------------------------
__global__ void sa_pass2(
    float* x, const float* w1, const float* g0, const float* b0,
    const float* s1sum, const float* s1sq,
    float* s2sum, float* s2sq, float invN, int NS)
{
    __shared__ float hs[32*CO];
    int m = blockIdx.x, t = threadIdx.x;

    float mean = s1sum[t] * invN;
    float var  = s1sq[t] * invN - mean * mean;
    float k    = rsqrtf(var + 1e-5f) * g0[t];
    float sh   = b0[t] - mean * k;

    long long base = (long long)m*NS*CO + t;
    for (int n = 0; n < NS; n++) {
        float h = x[base + (long long)n*CO] * k + sh;
        hs[n*CO + t] = h > 0.f ? h : 0.f;
    }
    __syncthreads();

    const float* wr = w1 + t*CO;
    float4 w[32];
#pragma unroll
    for (int c = 0; c < 32; c++)
        w[c] = make_float4(wr[4*c], wr[4*c+1], wr[4*c+2], wr[4*c+3]);

    float s = 0.f, q = 0.f;
    for (int n = 0; n < NS; n++) {
        const float4* h4 = (const float4*)(hs + n*CO);
        float acc = 0.f;
#pragma unroll
        for (int c = 0; c < 32; c++) {
            float4 h = h4[c];
            acc = fmaf(h.x, w[c].x, acc);
            acc = fmaf(h.y, w[c].y, acc);
            acc = fmaf(h.z, w[c].z, acc);
            acc = fmaf(h.w, w[c].w, acc);
        }
        x[base + (long long)n*CO] = acc;
        s += acc; q = fmaf(acc, acc, q);
    }
    atomicAdd(&s2sum[t], s);
    atomicAdd(&s2sq[t], q);
}

// ---------------------------------------------------------------------------
// Pass 3: BN2 + max over samples + ReLU -> f32 output columns.
// max(relu(x)) == relu(max(x)) since relu is monotone.
// ---------------------------------------------------------------------------
__global__ void sa_pass3(
    const float* x, const float* g1, const float* b1,
    const float* s2sum, const float* s2sq,
    float* outp, float invN, int NS)
{
    int m = blockIdx.x, t = threadIdx.x;
    float mean = s2sum[t] * invN;
    float var  = s2sq[t] * invN - mean * mean;
    float k    = rsqrtf(var + 1e-5f) * g1[t];
    float sh   = b1[t] - mean * k;

    long long base = (long long)m*NS*CO + t;
    float mx = -3.4e38f;
    for (int n = 0; n < NS; n++) {
        float v = x[base + (long long)n*CO] * k + sh;
        mx = v > mx ? v : mx;
    }
    mx = mx > 0.f ? mx : 0.f;
    outp[(long long)m*256 + t] = mx;
}

// ---------------------------------------------------------------------------
extern "C" void kernel_launch(void* const* d_in, const int* in_sizes, int n_in,
                              void* d_out, int out_size, void* d_ws, size_t ws_size,
                              hipStream_t stream)
{
    const float* xyz  = (const float*)d_in[0];
    const float* feat = (const float*)d_in[1];
    const float* nxyz = (const float*)d_in[2];
    const float* w00 = (const float*)d_in[5];
    const float* g00 = (const float*)d_in[6];
    const float* b00 = (const float*)d_in[7];
    const float* w01 = (const float*)d_in[8];
    const float* g01 = (const float*)d_in[9];
    const float* b01 = (const float*)d_in[10];
    const float* w10 = (const float*)d_in[11];
    const float* g10 = (const float*)d_in[12];
    const float* b10 = (const float*)d_in[13];
    const float* w11 = (const float*)d_in[14];
    const float* g11 = (const float*)d_in[15];
    const float* b11 = (const float*)d_in[16];
    float* out = (float*)d_out;

    // ws: stats 4KB | idx0 512KB | idx1 1MB | empty0/1 64KB | x (134 MB f32)
    char*  wsb    = (char*)d_ws;
    float* stats  = (float*)(wsb);
    int*   idx0   = (int*)(wsb + 4096);
    int*   idx1   = (int*)(wsb + 4096 + 524288);
    int*   empty0 = (int*)(wsb + 4096 + 524288 + 1048576);
    int*   empty1 = (int*)(wsb + 4096 + 524288 + 1048576 + 32768);
    float* x      = (float*)(wsb + 4096 + 524288 + 1048576 + 65536);

    StackSAModuleMSG_85761906966880_kernel<<<96, 256, 0, stream>>>(nxyz, out, stats);
    sa_ballq<<<32, 256, 0, stream>>>(xyz, nxyz, idx0, idx1, empty0, empty1);

    float* fout = out + MTOT*3;
    const float invN0 = 1.0f / (float)(MTOT*16);
    const float invN1 = 1.0f / (float)(MTOT*32);

    // scale 0 (r=0.2, ns=16)
    sa_pass1<<<MTOT, 128, 0, stream>>>(xyz, feat, nxyz, idx0, empty0, w00,
                                       x, stats + 0, stats + 128, 16);
    sa_pass2<<<MTOT, 128, 0, stream>>>(x, w01, g00, b00, stats + 0, stats + 128,
                                       stats + 256, stats + 384, invN0, 16);
    sa_pass3<<<MTOT, 128, 0, stream>>>(x, g01, b01, stats + 256, stats + 384,
                                       fout, invN0, 16);
    // scale 1 (r=0.4, ns=32)
    sa_pass1<<<MTOT, 128, 0, stream>>>(xyz, feat, nxyz, idx1, empty1, w10,
                                       x, stats + 512, stats + 640, 32);
    sa_pass2<<<MTOT, 128, 0, stream>>>(x, w11, g10, b10, stats + 512, stats + 640,
                                       stats + 768, stats + 896, invN1, 32);
    sa_pass3<<<MTOT, 128, 0, stream>>>(x, g11, b11, stats + 768, stats + 896,
                                       fout + 128, invN1, 32);

    hipError_t e = hipGetLastError();
    if (e != hipSuccess) EPR("[KL] enqueue err=%d (%s)\n", (int)e, hipGetErrorString(e));
}

// Round 12
// 2191.438 us; speedup vs baseline: 1.0210x; 1.0210x over previous
//
#include <hip/hip_runtime.h>
#include <stdio.h>

#define NBP   8192
#define MTOT  8192
#define CIN   64
#define C1    67
#define C1P   68
#define CO    128

#define EPR(...) do { fprintf(stderr, __VA_ARGS__); fflush(stderr); } while (0)

// ---------------------------------------------------------------------------
// Zero the 1024-float BN-stats region; write output 0 = new_xyz (f32 copy).
// ---------------------------------------------------------------------------
__global__ void StackSAModuleMSG_85761906966880_kernel(
    const float* nxyz, float* out, float* stats)
{
    int i = blockIdx.x * 256 + threadIdx.x;
    if (i < 1024) stats[i] = 0.f;
    if (i < MTOT*3) out[i] = nxyz[i];
}

// ---------------------------------------------------------------------------
// Ball query, both scales: ONE WAVE (64 lanes) PER QUERY. Each lane evaluates
// one candidate point's d2 in f64 (identical arithmetic to the sequential
// version); ballot + prefix-popcount assigns ascending-index slots; early
// exit once both scales are full. first-hit index derived from the wave-
// uniform ballot mask via ffsll (no cross-lane data movement needed).
// ---------------------------------------------------------------------------
__global__ void sa_ballq(
    const float* xyz, const float* new_xyz,
    int* idx0, int* idx1, int* empty0, int* empty1)
{
    const double r2a = 0.2 * 0.2;
    const double r2b = 0.4 * 0.4;
    int m    = blockIdx.x;
    int lane = threadIdx.x;
    int b    = m >> 11;
    int base = b * NBP;

    double nx = (double)new_xyz[3*m+0];
    double ny = (double)new_xyz[3*m+1];
    double nz = (double)new_xyz[3*m+2];
    double nn = nx*nx + ny*ny + nz*nz;

    int cnt0 = 0, cnt1 = 0;
    int first0 = base, first1 = base;
    unsigned long long lt = (1ull << lane) - 1ull;

    for (int j = 0; j < NBP; j += 64) {
        int gi = base + j + lane;
        double px = (double)xyz[3*gi+0];
        double py = (double)xyz[3*gi+1];
        double pz = (double)xyz[3*gi+2];
        double pp = px*px + py*py + pz*pz;
        double dt = nx*px + ny*py + nz*pz;
        double d2 = nn + pp - 2.0*dt;
        bool in0 = d2 < r2a;
        bool in1 = d2 < r2b;
        unsigned long long m0 = __ballot(in0);
        unsigned long long m1 = __ballot(in1);
        if (in0) {
            int p = cnt0 + __popcll(m0 & lt);
            if (p < 16) idx0[m*16 + p] = gi;
        }
        if (in1) {
            int p = cnt1 + __popcll(m1 & lt);
            if (p < 32) idx1[m*32 + p] = gi;
        }
        if (cnt0 == 0 && m0) first0 = base + j + (__ffsll((long long)m0) - 1);
        if (cnt1 == 0 && m1) first1 = base + j + (__ffsll((long long)m1) - 1);
        cnt0 += __popcll(m0);
        cnt1 += __popcll(m1);
        if (cnt0 >= 16 && cnt1 >= 32) break;
    }
    // pad unfilled slots with the first selected index (or base if empty)
    int c0 = cnt0 < 16 ? cnt0 : 16;
    int c1 = cnt1 < 32 ? cnt1 : 32;
    if (lane >= c0 && lane < 16) idx0[m*16 + lane] = first0;
    if (lane >= c1 && lane < 32) idx1[m*32 + lane] = first1;
    if (lane == 0) { empty0[m] = (cnt0 == 0); empty1[m] = (cnt1 == 0); }
}

// ---------------------------------------------------------------------------
// Pass 1: gather g=[xyz[idx]-new | feat[idx]] into LDS, x1 = g @ W0^T -> ws,
// accumulate layer-1 per-channel sum/sumsq. Block m, thread t = out channel.
// 4 independent accumulators break the fmaf dependency chain.
// ---------------------------------------------------------------------------
__global__ void sa_pass1(
    const float* xyz, const float* feat, const float* nxyz,
    const int* idx, const int* empty, const float* w0,
    float* x1, float* ssum, float* ssq, int NS)
{
    __shared__ float gs[32*C1P];
    __shared__ int   lidx[32];
    int m = blockIdx.x, t = threadIdx.x;
    if (t < NS) lidx[t] = idx[m*NS + t];
    __syncthreads();
    int emp = empty[m];
    for (int e = t; e < NS*C1P; e += 128) {
        int n = e / C1P, c = e - n*C1P;
        float v = 0.f;
        if (c < C1 && !emp) {
            int gi = lidx[n];
            v = (c < 3) ? (xyz[3*gi + c] - nxyz[3*m + c])
                        : feat[(long long)gi*CIN + (c-3)];
        }
        gs[e] = v;
    }
    __syncthreads();

    const float* wr = w0 + t*C1;
    float4 w[17];
#pragma unroll
    for (int c = 0; c < 16; c++)
        w[c] = make_float4(wr[4*c], wr[4*c+1], wr[4*c+2], wr[4*c+3]);
    w[16] = make_float4(wr[64], wr[65], wr[66], 0.f);

    float s = 0.f, q = 0.f;
    long long obase = (long long)m*NS*CO + t;
    for (int n = 0; n < NS; n++) {
        const float4* g4 = (const float4*)(gs + n*C1P);
        float a0 = 0.f, a1 = 0.f, a2 = 0.f, a3 = 0.f;
#pragma unroll
        for (int c = 0; c < 16; c += 4) {
            float4 g0 = g4[c],   g1 = g4[c+1], g2 = g4[c+2], g3 = g4[c+3];
            a0 = fmaf(g0.x, w[c].x,   a0); a0 = fmaf(g0.y, w[c].y,   a0);
            a0 = fmaf(g0.z, w[c].z,   a0); a0 = fmaf(g0.w, w[c].w,   a0);
            a1 = fmaf(g1.x, w[c+1].x, a1); a1 = fmaf(g1.y, w[c+1].y, a1);
            a1 = fmaf(g1.z, w[c+1].z, a1); a1 = fmaf(g1.w, w[c+1].w, a1);
            a2 = fmaf(g2.x, w[c+2].x, a2); a2 = fmaf(g2.y, w[c+2].y, a2);
            a2 = fmaf(g2.z, w[c+2].z, a2); a2 = fmaf(g2.w, w[c+2].w, a2);
            a3 = fmaf(g3.x, w[c+3].x, a3); a3 = fmaf(g3.y, w[c+3].y, a3);
            a3 = fmaf(g3.z, w[c+3].z, a3); a3 = fmaf(g3.w, w[c+3].w, a3);
        }
        float4 gl = g4[16];
        a0 = fmaf(gl.x, w[16].x, a0);
        a1 = fmaf(gl.y, w[16].y, a1);
        a2 = fmaf(gl.z, w[16].z, a2);
        float acc = (a0 + a1) + (a2 + a3);
        x1[obase + (long long)n*CO] = acc;
        s += acc; q = fmaf(acc, acc, q);
    }
    atomicAdd(&ssum[t], s);
    atomicAdd(&ssq[t], q);
}

// ---------------------------------------------------------------------------
// Pass 2: read x1, BN1+ReLU -> LDS, x2 = h @ W1^T written in place,
// accumulate layer-2 stats. Block-private rows: in-place is safe.
// ---------------------------------------------------------------------------
__global__ void sa_pass2(
    float* x, const float* w1, const float* g0, const float* b0,
    const float* s1sum, const float* s1sq,
    float* s2sum, float* s2sq, float invN, int NS)
{
    __shared__ float hs[32*CO];
    int m = blockIdx.x, t = threadIdx.x;

    float mean = s1sum[t] * invN;
    float var  = s1sq[t] * invN - mean * mean;
    float k    = rsqrtf(var + 1e-5f) * g0[t];
    float sh   = b0[t] - mean * k;

    long long base = (long long)m*NS*CO + t;
    for (int n = 0; n < NS; n++) {
        float h = x[base + (long long)n*CO] * k + sh;
        hs[n*CO + t] = h > 0.f ? h : 0.f;
    }
    __syncthreads();

    const float* wr = w1 + t*CO;
    float4 w[32];
#pragma unroll
    for (int c = 0; c < 32; c++)
        w[c] = make_float4(wr[4*c], wr[4*c+1], wr[4*c+2], wr[4*c+3]);

    float s = 0.f, q = 0.f;
    for (int n = 0; n < NS; n++) {
        const float4* h4 = (const float4*)(hs + n*CO);
        float a0 = 0.f, a1 = 0.f, a2 = 0.f, a3 = 0.f;
#pragma unroll
        for (int c = 0; c < 32; c += 4) {
            float4 h0 = h4[c],   h1 = h4[c+1], h2 = h4[c+2], h3 = h4[c+3];
            a0 = fmaf(h0.x, w[c].x,   a0); a0 = fmaf(h0.y, w[c].y,   a0);
            a0 = fmaf(h0.z, w[c].z,   a0); a0 = fmaf(h0.w, w[c].w,   a0);
            a1 = fmaf(h1.x, w[c+1].x, a1); a1 = fmaf(h1.y, w[c+1].y, a1);
            a1 = fmaf(h1.z, w[c+1].z, a1); a1 = fmaf(h1.w, w[c+1].w, a1);
            a2 = fmaf(h2.x, w[c+2].x, a2); a2 = fmaf(h2.y, w[c+2].y, a2);
            a2 = fmaf(h2.z, w[c+2].z, a2); a2 = fmaf(h2.w, w[c+2].w, a2);
            a3 = fmaf(h3.x, w[c+3].x, a3); a3 = fmaf(h3.y, w[c+3].y, a3);
            a3 = fmaf(h3.z, w[c+3].z, a3); a3 = fmaf(h3.w, w[c+3].w, a3);
        }
        float acc = (a0 + a1) + (a2 + a3);
        x[base + (long long)n*CO] = acc;
        s += acc; q = fmaf(acc, acc, q);
    }
    atomicAdd(&s2sum[t], s);
    atomicAdd(&s2sq[t], q);
}

// ---------------------------------------------------------------------------
// Pass 3: BN2 + max over samples + ReLU -> f32 output columns.
// max(relu(x)) == relu(max(x)) since relu is monotone.
// ---------------------------------------------------------------------------
__global__ void sa_pass3(
    const float* x, const float* g1, const float* b1,
    const float* s2sum, const float* s2sq,
    float* outp, float invN, int NS)
{
    int m = blockIdx.x, t = threadIdx.x;
    float mean = s2sum[t] * invN;
    float var  = s2sq[t] * invN - mean * mean;
    float k    = rsqrtf(var + 1e-5f) * g1[t];
    float sh   = b1[t] - mean * k;

    long long base = (long long)m*NS*CO + t;
    float mx = -3.4e38f;
    for (int n = 0; n < NS; n++) {
        float v = x[base + (long long)n*CO] * k + sh;
        mx = v > mx ? v : mx;
    }
    mx = mx > 0.f ? mx : 0.f;
    outp[(long long)m*256 + t] = mx;
}

// ---------------------------------------------------------------------------
extern "C" void kernel_launch(void* const* d_in, const int* in_sizes, int n_in,
                              void* d_out, int out_size, void* d_ws, size_t ws_size,
                              hipStream_t stream)
{
    const float* xyz  = (const float*)d_in[0];
    const float* feat = (const float*)d_in[1];
    const float* nxyz = (const float*)d_in[2];
    const float* w00 = (const float*)d_in[5];
    const float* g00 = (const float*)d_in[6];
    const float* b00 = (const float*)d_in[7];
    const float* w01 = (const float*)d_in[8];
    const float* g01 = (const float*)d_in[9];
    const float* b01 = (const float*)d_in[10];
    const float* w10 = (const float*)d_in[11];
    const float* g10 = (const float*)d_in[12];
    const float* b10 = (const float*)d_in[13];
    const float* w11 = (const float*)d_in[14];
    const float* g11 = (const float*)d_in[15];
    const float* b11 = (const float*)d_in[16];
    float* out = (float*)d_out;

    // ws: stats 4KB | idx0 512KB | idx1 1MB | empty0/1 64KB | x (134 MB f32)
    char*  wsb    = (char*)d_ws;
    float* stats  = (float*)(wsb);
    int*   idx0   = (int*)(wsb + 4096);
    int*   idx1   = (int*)(wsb + 4096 + 524288);
    int*   empty0 = (int*)(wsb + 4096 + 524288 + 1048576);
    int*   empty1 = (int*)(wsb + 4096 + 524288 + 1048576 + 32768);
    float* x      = (float*)(wsb + 4096 + 524288 + 1048576 + 65536);

    StackSAModuleMSG_85761906966880_kernel<<<96, 256, 0, stream>>>(nxyz, out, stats);
    sa_ballq<<<MTOT, 64, 0, stream>>>(xyz, nxyz, idx0, idx1, empty0, empty1);

    float* fout = out + MTOT*3;
    const float invN0 = 1.0f / (float)(MTOT*16);
    const float invN1 = 1.0f / (float)(MTOT*32);

    // scale 0 (r=0.2, ns=16)
    sa_pass1<<<MTOT, 128, 0, stream>>>(xyz, feat, nxyz, idx0, empty0, w00,
                                       x, stats + 0, stats + 128, 16);
    sa_pass2<<<MTOT, 128, 0, stream>>>(x, w01, g00, b00, stats + 0, stats + 128,
                                       stats + 256, stats + 384, invN0, 16);
    sa_pass3<<<MTOT, 128, 0, stream>>>(x, g01, b01, stats + 256, stats + 384,
                                       fout, invN0, 16);
    // scale 1 (r=0.4, ns=32)
    sa_pass1<<<MTOT, 128, 0, stream>>>(xyz, feat, nxyz, idx1, empty1, w10,
                                       x, stats + 512, stats + 640, 32);
    sa_pass2<<<MTOT, 128, 0, stream>>>(x, w11, g10, b10, stats + 512, stats + 640,
                                       stats + 768, stats + 896, invN1, 32);
    sa_pass3<<<MTOT, 128, 0, stream>>>(x, g11, b11, stats + 768, stats + 896,
                                       fout + 128, invN1, 32);

    hipError_t e = hipGetLastError();
    if (e != hipSuccess) EPR("[KL] enqueue err=%d (%s)\n", (int)e, hipGetErrorString(e));
}

// Round 13
// 1205.171 us; speedup vs baseline: 1.8565x; 1.8184x over previous
//
#include <hip/hip_runtime.h>
#include <stdio.h>

#define NBP   8192
#define MTOT  8192
#define CIN   64
#define C1    67
#define C1P   68
#define CO    128

#define EPR(...) do { fprintf(stderr, __VA_ARGS__); fflush(stderr); } while (0)

// ---------------------------------------------------------------------------
// Zero the 1024-float BN-stats region; write output 0 = new_xyz (f32 copy).
// ---------------------------------------------------------------------------
__global__ void __launch_bounds__(256, 1) StackSAModuleMSG_85761906966880_kernel(
    const float* nxyz, float* out, float* stats)
{
    int i = blockIdx.x * 256 + threadIdx.x;
    if (i < 1024) stats[i] = 0.f;
    if (i < MTOT*3) out[i] = nxyz[i];
}

// ---------------------------------------------------------------------------
// Ball query, both scales: one wave per query; f64 d2 (matches np gold).
// ---------------------------------------------------------------------------
__global__ void __launch_bounds__(64, 1) sa_ballq(
    const float* xyz, const float* new_xyz,
    int* idx0, int* idx1, int* empty0, int* empty1)
{
    const double r2a = 0.2 * 0.2;
    const double r2b = 0.4 * 0.4;
    int m    = blockIdx.x;
    int lane = threadIdx.x;
    int b    = m >> 11;
    int base = b * NBP;

    double nx = (double)new_xyz[3*m+0];
    double ny = (double)new_xyz[3*m+1];
    double nz = (double)new_xyz[3*m+2];
    double nn = nx*nx + ny*ny + nz*nz;

    int cnt0 = 0, cnt1 = 0;
    int first0 = base, first1 = base;
    unsigned long long lt = (1ull << lane) - 1ull;

    for (int j = 0; j < NBP; j += 64) {
        int gi = base + j + lane;
        double px = (double)xyz[3*gi+0];
        double py = (double)xyz[3*gi+1];
        double pz = (double)xyz[3*gi+2];
        double pp = px*px + py*py + pz*pz;
        double dt = nx*px + ny*py + nz*pz;
        double d2 = nn + pp - 2.0*dt;
        bool in0 = d2 < r2a;
        bool in1 = d2 < r2b;
        unsigned long long m0 = __ballot(in0);
        unsigned long long m1 = __ballot(in1);
        if (in0) {
            int p = cnt0 + __popcll(m0 & lt);
            if (p < 16) idx0[m*16 + p] = gi;
        }
        if (in1) {
            int p = cnt1 + __popcll(m1 & lt);
            if (p < 32) idx1[m*32 + p] = gi;
        }
        if (cnt0 == 0 && m0) first0 = base + j + (__ffsll((long long)m0) - 1);
        if (cnt1 == 0 && m1) first1 = base + j + (__ffsll((long long)m1) - 1);
        cnt0 += __popcll(m0);
        cnt1 += __popcll(m1);
        if (cnt0 >= 16 && cnt1 >= 32) break;
    }
    int c0 = cnt0 < 16 ? cnt0 : 16;
    int c1 = cnt1 < 32 ? cnt1 : 32;
    if (lane >= c0 && lane < 16) idx0[m*16 + lane] = first0;
    if (lane >= c1 && lane < 32) idx1[m*32 + lane] = first1;
    if (lane == 0) { empty0[m] = (cnt0 == 0); empty1[m] = (cnt1 == 0); }
}

// ---------------------------------------------------------------------------
// Pass 1: gather -> LDS, x1 = g @ W0^T -> ws, layer-1 sum/sumsq.
// __launch_bounds__(128,1): w0 row (68 floats) must live in registers.
// ---------------------------------------------------------------------------
__global__ void __launch_bounds__(128, 1) sa_pass1(
    const float* xyz, const float* feat, const float* nxyz,
    const int* idx, const int* empty, const float* w0,
    float* x1, float* ssum, float* ssq, int NS)
{
    __shared__ float gs[32*C1P];
    __shared__ int   lidx[32];
    int m = blockIdx.x, t = threadIdx.x;
    if (t < NS) lidx[t] = idx[m*NS + t];
    __syncthreads();
    int emp = empty[m];
    for (int e = t; e < NS*C1P; e += 128) {
        int n = e / C1P, c = e - n*C1P;
        float v = 0.f;
        if (c < C1 && !emp) {
            int gi = lidx[n];
            v = (c < 3) ? (xyz[3*gi + c] - nxyz[3*m + c])
                        : feat[(long long)gi*CIN + (c-3)];
        }
        gs[e] = v;
    }
    __syncthreads();

    const float* wr = w0 + t*C1;
    float4 w[17];
#pragma unroll
    for (int c = 0; c < 16; c++)
        w[c] = make_float4(wr[4*c], wr[4*c+1], wr[4*c+2], wr[4*c+3]);
    w[16] = make_float4(wr[64], wr[65], wr[66], 0.f);

    float s = 0.f, q = 0.f;
    long long obase = (long long)m*NS*CO + t;
    for (int n = 0; n < NS; n++) {
        const float4* g4 = (const float4*)(gs + n*C1P);
        float a0 = 0.f, a1 = 0.f, a2 = 0.f, a3 = 0.f;
#pragma unroll
        for (int c = 0; c < 16; c += 4) {
            float4 g0 = g4[c],   g1 = g4[c+1], g2 = g4[c+2], g3 = g4[c+3];
            a0 = fmaf(g0.x, w[c].x,   a0); a0 = fmaf(g0.y, w[c].y,   a0);
            a0 = fmaf(g0.z, w[c].z,   a0); a0 = fmaf(g0.w, w[c].w,   a0);
            a1 = fmaf(g1.x, w[c+1].x, a1); a1 = fmaf(g1.y, w[c+1].y, a1);
            a1 = fmaf(g1.z, w[c+1].z, a1); a1 = fmaf(g1.w, w[c+1].w, a1);
            a2 = fmaf(g2.x, w[c+2].x, a2); a2 = fmaf(g2.y, w[c+2].y, a2);
            a2 = fmaf(g2.z, w[c+2].z, a2); a2 = fmaf(g2.w, w[c+2].w, a2);
            a3 = fmaf(g3.x, w[c+3].x, a3); a3 = fmaf(g3.y, w[c+3].y, a3);
            a3 = fmaf(g3.z, w[c+3].z, a3); a3 = fmaf(g3.w, w[c+3].w, a3);
        }
        float4 gl = g4[16];
        a0 = fmaf(gl.x, w[16].x, a0);
        a1 = fmaf(gl.y, w[16].y, a1);
        a2 = fmaf(gl.z, w[16].z, a2);
        float acc = (a0 + a1) + (a2 + a3);
        x1[obase + (long long)n*CO] = acc;
        s += acc; q = fmaf(acc, acc, q);
    }
    atomicAdd(&ssum[t], s);
    atomicAdd(&ssq[t], q);
}

// ---------------------------------------------------------------------------
// Pass 2: read x1, BN1+ReLU -> LDS, x2 = h @ W1^T in place, layer-2 stats.
// __launch_bounds__(128,1): w1 row (128 floats) must live in registers.
// ---------------------------------------------------------------------------
__global__ void __launch_bounds__(128, 1) sa_pass2(
    float* x, const float* w1, const float* g0, const float* b0,
    const float* s1sum, const float* s1sq,
    float* s2sum, float* s2sq, float invN, int NS)
{
    __shared__ float hs[32*CO];
    int m = blockIdx.x, t = threadIdx.x;

    float mean = s1sum[t] * invN;
    float var  = s1sq[t] * invN - mean * mean;
    float k    = rsqrtf(var + 1e-5f) * g0[t];
    float sh   = b0[t] - mean * k;

    long long base = (long long)m*NS*CO + t;
    for (int n = 0; n < NS; n++) {
        float h = x[base + (long long)n*CO] * k + sh;
        hs[n*CO + t] = h > 0.f ? h : 0.f;
    }
    __syncthreads();

    const float* wr = w1 + t*CO;
    float4 w[32];
#pragma unroll
    for (int c = 0; c < 32; c++)
        w[c] = make_float4(wr[4*c], wr[4*c+1], wr[4*c+2], wr[4*c+3]);

    float s = 0.f, q = 0.f;
    for (int n = 0; n < NS; n++) {
        const float4* h4 = (const float4*)(hs + n*CO);
        float a0 = 0.f, a1 = 0.f, a2 = 0.f, a3 = 0.f;
#pragma unroll
        for (int c = 0; c < 32; c += 4) {
            float4 h0 = h4[c],   h1 = h4[c+1], h2 = h4[c+2], h3 = h4[c+3];
            a0 = fmaf(h0.x, w[c].x,   a0); a0 = fmaf(h0.y, w[c].y,   a0);
            a0 = fmaf(h0.z, w[c].z,   a0); a0 = fmaf(h0.w, w[c].w,   a0);
            a1 = fmaf(h1.x, w[c+1].x, a1); a1 = fmaf(h1.y, w[c+1].y, a1);
            a1 = fmaf(h1.z, w[c+1].z, a1); a1 = fmaf(h1.w, w[c+1].w, a1);
            a2 = fmaf(h2.x, w[c+2].x, a2); a2 = fmaf(h2.y, w[c+2].y, a2);
            a2 = fmaf(h2.z, w[c+2].z, a2); a2 = fmaf(h2.w, w[c+2].w, a2);
            a3 = fmaf(h3.x, w[c+3].x, a3); a3 = fmaf(h3.y, w[c+3].y, a3);
            a3 = fmaf(h3.z, w[c+3].z, a3); a3 = fmaf(h3.w, w[c+3].w, a3);
        }
        float acc = (a0 + a1) + (a2 + a3);
        x[base + (long long)n*CO] = acc;
        s += acc; q = fmaf(acc, acc, q);
    }
    atomicAdd(&s2sum[t], s);
    atomicAdd(&s2sq[t], q);
}

// ---------------------------------------------------------------------------
// Pass 3: BN2 + max over samples + ReLU -> f32 output columns.
// ---------------------------------------------------------------------------
__global__ void __launch_bounds__(128, 1) sa_pass3(
    const float* x, const float* g1, const float* b1,
    const float* s2sum, const float* s2sq,
    float* outp, float invN, int NS)
{
    int m = blockIdx.x, t = threadIdx.x;
    float mean = s2sum[t] * invN;
    float var  = s2sq[t] * invN - mean * mean;
    float k    = rsqrtf(var + 1e-5f) * g1[t];
    float sh   = b1[t] - mean * k;

    long long base = (long long)m*NS*CO + t;
    float mx = -3.4e38f;
    for (int n = 0; n < NS; n++) {
        float v = x[base + (long long)n*CO] * k + sh;
        mx = v > mx ? v : mx;
    }
    mx = mx > 0.f ? mx : 0.f;
    outp[(long long)m*256 + t] = mx;
}

// ---------------------------------------------------------------------------
extern "C" void kernel_launch(void* const* d_in, const int* in_sizes, int n_in,
                              void* d_out, int out_size, void* d_ws, size_t ws_size,
                              hipStream_t stream)
{
    const float* xyz  = (const float*)d_in[0];
    const float* feat = (const float*)d_in[1];
    const float* nxyz = (const float*)d_in[2];
    const float* w00 = (const float*)d_in[5];
    const float* g00 = (const float*)d_in[6];
    const float* b00 = (const float*)d_in[7];
    const float* w01 = (const float*)d_in[8];
    const float* g01 = (const float*)d_in[9];
    const float* b01 = (const float*)d_in[10];
    const float* w10 = (const float*)d_in[11];
    const float* g10 = (const float*)d_in[12];
    const float* b10 = (const float*)d_in[13];
    const float* w11 = (const float*)d_in[14];
    const float* g11 = (const float*)d_in[15];
    const float* b11 = (const float*)d_in[16];
    float* out = (float*)d_out;

    // ws: stats 4KB | idx0 512KB | idx1 1MB | empty0/1 64KB | x (134 MB f32)
    char*  wsb    = (char*)d_ws;
    float* stats  = (float*)(wsb);
    int*   idx0   = (int*)(wsb + 4096);
    int*   idx1   = (int*)(wsb + 4096 + 524288);
    int*   empty0 = (int*)(wsb + 4096 + 524288 + 1048576);
    int*   empty1 = (int*)(wsb + 4096 + 524288 + 1048576 + 32768);
    float* x      = (float*)(wsb + 4096 + 524288 + 1048576 + 65536);

    StackSAModuleMSG_85761906966880_kernel<<<96, 256, 0, stream>>>(nxyz, out, stats);
    sa_ballq<<<MTOT, 64, 0, stream>>>(xyz, nxyz, idx0, idx1, empty0, empty1);

    float* fout = out + MTOT*3;
    const float invN0 = 1.0f / (float)(MTOT*16);
    const float invN1 = 1.0f / (float)(MTOT*32);

    // scale 0 (r=0.2, ns=16)
    sa_pass1<<<MTOT, 128, 0, stream>>>(xyz, feat, nxyz, idx0, empty0, w00,
                                       x, stats + 0, stats + 128, 16);
    sa_pass2<<<MTOT, 128, 0, stream>>>(x, w01, g00, b00, stats + 0, stats + 128,
                                       stats + 256, stats + 384, invN0, 16);
    sa_pass3<<<MTOT, 128, 0, stream>>>(x, g01, b01, stats + 256, stats + 384,
                                       fout, invN0, 16);
    // scale 1 (r=0.4, ns=32)
    sa_pass1<<<MTOT, 128, 0, stream>>>(xyz, feat, nxyz, idx1, empty1, w10,
                                       x, stats + 512, stats + 640, 32);
    sa_pass2<<<MTOT, 128, 0, stream>>>(x, w11, g10, b10, stats + 512, stats + 640,
                                       stats + 768, stats + 896, invN1, 32);
    sa_pass3<<<MTOT, 128, 0, stream>>>(x, g11, b11, stats + 768, stats + 896,
                                       fout + 128, invN1, 32);

    hipError_t e = hipGetLastError();
    if (e != hipSuccess) EPR("[KL] enqueue err=%d (%s)\n", (int)e, hipGetErrorString(e));
}